// Round 2
// baseline (9671.235 us; speedup 1.0000x reference)
//
#include <hip/hip_runtime.h>
#include <hip/hip_bf16.h>
#include <hip/hip_fp16.h>

typedef _Float16 f16;
typedef __hip_bfloat16 bf16;
typedef short bf16x8 __attribute__((ext_vector_type(8)));
typedef float f32x4 __attribute__((ext_vector_type(4)));
typedef _Float16 f16x2 __attribute__((ext_vector_type(2)));

#define HDIM 256
#define G4   1024
#define TT   2048
#define NB   64
#define NTOK (64*2048)
#define MPAD 384   // 341 padded to 384 (6 x 64)

// ---------------- helpers ----------------
__device__ __forceinline__ float dot2f(unsigned a, unsigned b, float c) {
#if __has_builtin(__builtin_amdgcn_fdot2)
    return __builtin_amdgcn_fdot2(__builtin_bit_cast(f16x2, a),
                                  __builtin_bit_cast(f16x2, b), c, false);
#else
    f16x2 x = __builtin_bit_cast(f16x2, a), y = __builtin_bit_cast(f16x2, b);
    return c + (float)x[0]*(float)y[0] + (float)x[1]*(float)y[1];
#endif
}

__device__ __forceinline__ float gelu_tanh(float x) {
    // jax.nn.gelu default (approximate=True)
    float x3 = x*x*x;
    float t = tanhf(0.7978845608028654f * (x + 0.044715f * x3));
    return 0.5f * x * (1.0f + t);
}

// ---------------- prep: dtype conversion + padding ----------------
__global__ void k_prep_wr(const float* __restrict__ W, const float* __restrict__ R,
                          bf16* __restrict__ Wb, f16* __restrict__ Rf) {
    int i = blockIdx.x*256 + threadIdx.x;          // 262144 total
    Wb[i] = __float2bfloat16(W[i]);
    Rf[i] = (f16)R[i];
}

__global__ void k_prep_gu(const float* __restrict__ gW, const float* __restrict__ uW,
                          const float* __restrict__ gb, const float* __restrict__ ub,
                          bf16* __restrict__ gWb, bf16* __restrict__ uWb,
                          float* __restrict__ gbp, float* __restrict__ ubp) {
    int i = blockIdx.x*256 + threadIdx.x;          // 384*256 total
    int r = i >> 8, c = i & 255;
    gWb[i] = __float2bfloat16(r < 341 ? gW[r*256 + c] : 0.f);
    uWb[i] = __float2bfloat16(r < 341 ? uW[r*256 + c] : 0.f);
    if (i < 384) {
        gbp[i] = i < 341 ? gb[i] : 0.f;
        ubp[i] = i < 341 ? ub[i] : 0.f;
    }
}

__global__ void k_prep_down(const float* __restrict__ dW, bf16* __restrict__ dWb) {
    int i = blockIdx.x*256 + threadIdx.x;          // 256*384 total
    int r = i / 384, c = i % 384;
    dWb[i] = __float2bfloat16(c < 341 ? dW[r*341 + c] : 0.f);
}

// ---------------- LayerNorm 1: f32 -> bf16 ----------------
__global__ __launch_bounds__(256) void k_ln1(const float* __restrict__ x,
        const float* __restrict__ w, const float* __restrict__ b,
        bf16* __restrict__ nx) {
    int wave = threadIdx.x >> 6, lane = threadIdx.x & 63;
    long tok = (long)blockIdx.x * 4 + wave;
    float4 v = ((const float4*)(x + tok*HDIM))[lane];
    float s = v.x + v.y + v.z + v.w;
    float q = v.x*v.x + v.y*v.y + v.z*v.z + v.w*v.w;
    #pragma unroll
    for (int m = 1; m < 64; m <<= 1) { s += __shfl_xor(s, m, 64); q += __shfl_xor(q, m, 64); }
    float mean = s * (1.0f/HDIM);
    float rs = rsqrtf(q*(1.0f/HDIM) - mean*mean + 1e-5f);
    float4 wv = ((const float4*)w)[lane];
    float4 bv = ((const float4*)b)[lane];
    bf16 tmp[4];
    tmp[0] = __float2bfloat16((v.x-mean)*rs*wv.x + bv.x);
    tmp[1] = __float2bfloat16((v.y-mean)*rs*wv.y + bv.y);
    tmp[2] = __float2bfloat16((v.z-mean)*rs*wv.z + bv.z);
    tmp[3] = __float2bfloat16((v.w-mean)*rs*wv.w + bv.w);
    *(ushort4*)(nx + tok*HDIM + lane*4) = *(ushort4*)tmp;
}

// ---------------- LayerNorm 2 + residual: f16 mlp + f32 x -> f32 out ----------------
__global__ __launch_bounds__(256) void k_ln2(const f16* __restrict__ mlp,
        const float* __restrict__ x, const float* __restrict__ w,
        const float* __restrict__ b, float* __restrict__ out) {
    int wave = threadIdx.x >> 6, lane = threadIdx.x & 63;
    long tok = (long)blockIdx.x * 4 + wave;
    const f16* mr = mlp + tok*HDIM + lane*4;
    float4 v; v.x = (float)mr[0]; v.y = (float)mr[1]; v.z = (float)mr[2]; v.w = (float)mr[3];
    float s = v.x + v.y + v.z + v.w;
    float q = v.x*v.x + v.y*v.y + v.z*v.z + v.w*v.w;
    #pragma unroll
    for (int m = 1; m < 64; m <<= 1) { s += __shfl_xor(s, m, 64); q += __shfl_xor(q, m, 64); }
    float mean = s * (1.0f/HDIM);
    float rs = rsqrtf(q*(1.0f/HDIM) - mean*mean + 1e-5f);
    float4 wv = ((const float4*)w)[lane];
    float4 bv = ((const float4*)b)[lane];
    float4 xv = ((const float4*)(x + tok*HDIM))[lane];
    float4 ov;
    ov.x = (v.x-mean)*rs*wv.x + bv.x + xv.x;
    ov.y = (v.y-mean)*rs*wv.y + bv.y + xv.y;
    ov.z = (v.z-mean)*rs*wv.z + bv.z + xv.z;
    ov.w = (v.w-mean)*rs*wv.w + bv.w + xv.w;
    ((float4*)(out + tok*HDIM))[lane] = ov;
}

// ---------------- GEMM: C[M x N] = A[M x K] * B[N x K]^T + bias ----------------
enum { MODE_F16 = 0, MODE_GELU_F16 = 1, MODE_MUL_BF16 = 2 };

template<int MODE>
__global__ __launch_bounds__(256) void k_gemm(
    const bf16* __restrict__ A, const bf16* __restrict__ Bm,
    const float* __restrict__ bias, void* __restrict__ Cv,
    const f16* __restrict__ gatebuf,
    int K, int lda, int ldb, int ldc, int ldg)
{
    // BM=128, BN=64, BK=64; rows stored as 64 bf16 = 128B = 8x16B slots, XOR-swizzled
    __shared__ char Al[128*128];
    __shared__ char Bl[64*128];
    const int tid = threadIdx.x;
    const long bm = (long)blockIdx.x * 128;
    const int bn = blockIdx.y * 64;
    const int wave = tid >> 6, lane = tid & 63;
    const int wm = wave >> 1, wn = wave & 1;        // 2x2 waves, each 64x32
    const int l16 = lane & 15, lq = lane >> 4;
    f32x4 acc[4][2] = {};
    for (int k0 = 0; k0 < K; k0 += 64) {
        #pragma unroll
        for (int p = 0; p < 4; ++p) {               // A: 128 rows x 8 chunks
            int ci = tid + p*256;
            int row = ci >> 3, s = ci & 7;
            uint4 d = *(const uint4*)(A + (bm + row)*lda + k0 + s*8);
            *(uint4*)(Al + row*128 + ((s ^ (row&7))<<4)) = d;
        }
        #pragma unroll
        for (int p = 0; p < 2; ++p) {               // B: 64 rows x 8 chunks
            int ci = tid + p*256;
            int row = ci >> 3, s = ci & 7;
            uint4 d = *(const uint4*)(Bm + (long)(bn + row)*ldb + k0 + s*8);
            *(uint4*)(Bl + row*128 + ((s ^ (row&7))<<4)) = d;
        }
        __syncthreads();
        #pragma unroll
        for (int kc = 0; kc < 2; ++kc) {
            bf16x8 bf[2];
            #pragma unroll
            for (int fn = 0; fn < 2; ++fn) {
                int row = wn*32 + fn*16 + l16;
                int slot = (kc<<2) + lq;
                bf[fn] = *(const bf16x8*)(Bl + row*128 + ((slot ^ (row&7))<<4));
            }
            #pragma unroll
            for (int fm = 0; fm < 4; ++fm) {
                int row = wm*64 + fm*16 + l16;
                int slot = (kc<<2) + lq;
                bf16x8 af = *(const bf16x8*)(Al + row*128 + ((slot ^ (row&7))<<4));
                acc[fm][0] = __builtin_amdgcn_mfma_f32_16x16x32_bf16(af, bf[0], acc[fm][0], 0,0,0);
                acc[fm][1] = __builtin_amdgcn_mfma_f32_16x16x32_bf16(af, bf[1], acc[fm][1], 0,0,0);
            }
        }
        __syncthreads();
    }
    #pragma unroll
    for (int fm = 0; fm < 4; ++fm) {
        #pragma unroll
        for (int fn = 0; fn < 2; ++fn) {
            int n = bn + wn*32 + fn*16 + l16;
            float bv = bias[n];
            #pragma unroll
            for (int r = 0; r < 4; ++r) {
                long m = bm + wm*64 + fm*16 + lq*4 + r;
                float v = acc[fm][fn][r] + bv;
                if constexpr (MODE == MODE_F16) {
                    ((f16*)Cv)[m*ldc + n] = (f16)v;
                } else if constexpr (MODE == MODE_GELU_F16) {
                    ((f16*)Cv)[m*ldc + n] = (f16)gelu_tanh(v);
                } else {
                    float g = (float)gatebuf[m*ldg + n];
                    ((bf16*)Cv)[m*ldc + n] = __float2bfloat16(g * v);
                }
            }
        }
    }
}

// ---------------- sLSTM scan: 64 blocks (1 batch each), 1024 threads ----------------
// Thread t owns gate row g=t. R row: 192 elems in 24 uint4 VGPRs, 64 elems in LDS.
// All threads redundantly compute the state epilogue for j=t&255 (4 identical
// replicas); threads<256 publish h. xW load software-pipelined one step ahead.
#define SCAN_SMEM (1024*128 + 512 + 4096)

__global__ __launch_bounds__(1024) void k_scan(
    const f16* __restrict__ xW, const f16* __restrict__ Rf,
    bf16* __restrict__ h_out)
{
    extern __shared__ char sm[];
    char* R_lds   = sm;                              // 1024 rows x 128B (swizzled)
    unsigned* h_u = (unsigned*)(sm + 1024*128);      // 128 u32 = 256 f16 (h pairs)
    float* pre    = (float*)(sm + 1024*128 + 512);   // 1024 f32
    const int tid = threadIdx.x;
    const int b = blockIdx.x;
    const int g = tid;
    const int j = tid & 255;

    // Load R row g: 32 uint4. First 24 -> VGPRs, last 8 -> swizzled LDS.
    const uint4* rp = (const uint4*)(Rf + (long)g*256);
    uint4 Rq[24];
    #pragma unroll
    for (int q = 0; q < 24; ++q) Rq[q] = rp[q];
    #pragma unroll
    for (int s = 0; s < 8; ++s)
        *(uint4*)(R_lds + g*128 + ((s ^ (g&7))<<4)) = rp[24+s];
    if (tid < 128) h_u[tid] = 0u;

    float cst = 0.f, nst = 0.f, mst = 0.f;
    const f16* xptr = xW + (long)b * TT * G4 + g;
    bf16* hrow = h_out + (long)b * TT * HDIM;
    float xw = (float)*xptr;                         // step-0 value
    __syncthreads();

    for (int t = 0; t < TT; ++t) {
        // prefetch next step's xW one full iteration ahead (hides HBM latency).
        // Final iteration reads one row past xW: lands in the next ws region, unused.
        xptr += G4;
        f16 xw_nxt = *xptr;

        float a0 = 0.f, a1 = 0.f, a2 = 0.f, a3 = 0.f;
        const uint4* h4 = (const uint4*)h_u;         // broadcast reads
        #pragma unroll
        for (int q = 0; q < 24; ++q) {
            uint4 hv = h4[q];
            a0 = dot2f(Rq[q].x, hv.x, a0);
            a1 = dot2f(Rq[q].y, hv.y, a1);
            a2 = dot2f(Rq[q].z, hv.z, a2);
            a3 = dot2f(Rq[q].w, hv.w, a3);
        }
        #pragma unroll
        for (int s = 0; s < 8; ++s) {
            uint4 hv = h4[24+s];
            uint4 rv = *(const uint4*)(R_lds + g*128 + ((s ^ (g&7))<<4));
            a0 = dot2f(rv.x, hv.x, a0);
            a1 = dot2f(rv.y, hv.y, a1);
            a2 = dot2f(rv.z, hv.z, a2);
            a3 = dot2f(rv.w, hv.w, a3);
        }
        pre[g] = (a0 + a1) + (a2 + a3) + xw;
        __syncthreads();

        // Epilogue: all 1024 threads compute state for j = tid&255 (x4 replicas,
        // identical deterministic values) -> no idle waves.
        float zp = pre[j], li = pre[256+j], lf = pre[512+j], op = pre[768+j];
        float e = __expf(-2.0f * fabsf(zp));
        float z = copysignf((1.0f - e) / (1.0f + e), zp);
        float o = 1.0f / (1.0f + __expf(-op));
        float mn = fmaxf(lf + mst, li);
        float ig = __expf(li - mn);
        float fg = __expf(lf + mst - mn);
        cst = fg*cst + ig*z;
        nst = fg*nst + ig;
        mst = mn;
        float h = o * (cst / nst);
        if (tid < HDIM) {
            ((f16*)h_u)[tid] = (f16)h;
            hrow[tid] = __float2bfloat16(h);
        }
        __syncthreads();

        xw = (float)xw_nxt;
        hrow += HDIM;
    }
}

// ---------------- launch ----------------
extern "C" void kernel_launch(void* const* d_in, const int* in_sizes, int n_in,
                              void* d_out, int out_size, void* d_ws, size_t ws_size,
                              hipStream_t stream) {
    const float* x     = (const float*)d_in[0];
    const float* ln1w  = (const float*)d_in[1];
    const float* ln1b  = (const float*)d_in[2];
    const float* W     = (const float*)d_in[3];
    const float* R     = (const float*)d_in[4];
    const float* bg    = (const float*)d_in[5];
    const float* upW   = (const float*)d_in[6];
    const float* upb   = (const float*)d_in[7];
    const float* gateW = (const float*)d_in[8];
    const float* gateb = (const float*)d_in[9];
    const float* downW = (const float*)d_in[10];
    const float* downb = (const float*)d_in[11];
    const float* ln2w  = (const float*)d_in[12];
    const float* ln2b  = (const float*)d_in[13];

    char* ws = (char*)d_ws;
    size_t off = 0;
    auto alloc = [&](size_t bytes) { char* p = ws + off; off += (bytes + 255) & ~255ULL; return p; };
    f16*  mlp16   = (f16*)alloc((size_t)NTOK*HDIM*2);     // holds nx first, then mlp (disjoint lifetimes)
    char* regionB = alloc((size_t)NTOK*G4*2);             // xW, then gate_out+prod
    bf16* h       = (bf16*)alloc((size_t)NTOK*HDIM*2);
    bf16* Wb      = (bf16*)alloc(262144*2);
    f16*  Rf      = (f16*)alloc(262144*2);
    bf16* gWb     = (bf16*)alloc((size_t)MPAD*256*2);
    bf16* uWb     = (bf16*)alloc((size_t)MPAD*256*2);
    bf16* dWb     = (bf16*)alloc((size_t)256*MPAD*2);
    float* gbp    = (float*)alloc(MPAD*4);
    float* ubp    = (float*)alloc(MPAD*4);

    bf16* nx       = (bf16*)mlp16;                        // phase 1 use of that region
    f16*  xWb      = (f16*)regionB;                       // 131072 x 1024 f16
    f16*  gate_out = (f16*)regionB;                       // reuse after scan: 131072 x 384 f16
    bf16* prod     = (bf16*)(regionB + (size_t)NTOK*MPAD*2);

    hipFuncSetAttribute(reinterpret_cast<const void*>(&k_scan),
                        hipFuncAttributeMaxDynamicSharedMemorySize, SCAN_SMEM);

    k_prep_wr  <<<1024, 256, 0, stream>>>(W, R, Wb, Rf);
    k_prep_gu  <<<384, 256, 0, stream>>>(gateW, upW, gateb, upb, gWb, uWb, gbp, ubp);
    k_prep_down<<<384, 256, 0, stream>>>(downW, dWb);
    k_ln1      <<<NTOK/4, 256, 0, stream>>>(x, ln1w, ln1b, nx);
    // xW = nx @ W^T + b   (f16 out)
    k_gemm<MODE_F16><<<dim3(1024, 16), 256, 0, stream>>>(nx, Wb, bg, xWb, nullptr, 256, 256, 256, 1024, 0);
    // sequential sLSTM scan
    k_scan     <<<64, 1024, SCAN_SMEM, stream>>>(xWb, Rf, h);
    // gate = gelu(h @ gateW^T + gate_b)  (f16)
    k_gemm<MODE_GELU_F16><<<dim3(1024, 6), 256, 0, stream>>>(h, gWb, gbp, gate_out, nullptr, 256, 256, 256, MPAD, 0);
    // prod = gate * (h @ upW^T + up_b)   (bf16, padded cols auto-zero)
    k_gemm<MODE_MUL_BF16><<<dim3(1024, 6), 256, 0, stream>>>(h, uWb, ubp, prod, gate_out, 256, 256, 256, MPAD, MPAD);
    // mlp = prod @ downW^T + down_b      (f16 out, K=384)
    k_gemm<MODE_F16><<<dim3(1024, 4), 256, 0, stream>>>(prod, dWb, downb, mlp16, nullptr, MPAD, MPAD, MPAD, HDIM, 0);
    // out = LN(mlp) + x
    k_ln2      <<<NTOK/4, 256, 0, stream>>>(mlp16, x, ln2w, ln2b, (float*)d_out);
}

// Round 3
// 4302.236 us; speedup vs baseline: 2.2480x; 2.2480x over previous
//
#include <hip/hip_runtime.h>
#include <hip/hip_bf16.h>
#include <hip/hip_fp16.h>

typedef _Float16 f16;
typedef __hip_bfloat16 bf16;
typedef short bf16x8 __attribute__((ext_vector_type(8)));
typedef float f32x4 __attribute__((ext_vector_type(4)));
typedef _Float16 f16x2 __attribute__((ext_vector_type(2)));

#define HDIM 256
#define G4   1024
#define TT   2048
#define NB   64
#define NTOK (64*2048)
#define MPAD 384   // 341 padded to 384 (6 x 64)

// ---------------- helpers ----------------
__device__ __forceinline__ float dot2f(unsigned a, unsigned b, float c) {
#if __has_builtin(__builtin_amdgcn_fdot2)
    return __builtin_amdgcn_fdot2(__builtin_bit_cast(f16x2, a),
                                  __builtin_bit_cast(f16x2, b), c, false);
#else
    f16x2 x = __builtin_bit_cast(f16x2, a), y = __builtin_bit_cast(f16x2, b);
    return c + (float)x[0]*(float)y[0] + (float)x[1]*(float)y[1];
#endif
}

__device__ __forceinline__ float gelu_tanh(float x) {
    // jax.nn.gelu default (approximate=True)
    float x3 = x*x*x;
    float t = tanhf(0.7978845608028654f * (x + 0.044715f * x3));
    return 0.5f * x * (1.0f + t);
}

// ---------------- prep: dtype conversion + padding ----------------
__global__ void k_prep_wr(const float* __restrict__ W, const float* __restrict__ R,
                          bf16* __restrict__ Wb, f16* __restrict__ Rf) {
    int i = blockIdx.x*256 + threadIdx.x;          // 262144 total
    Wb[i] = __float2bfloat16(W[i]);
    Rf[i] = (f16)R[i];
}

__global__ void k_prep_gu(const float* __restrict__ gW, const float* __restrict__ uW,
                          const float* __restrict__ gb, const float* __restrict__ ub,
                          bf16* __restrict__ gWb, bf16* __restrict__ uWb,
                          float* __restrict__ gbp, float* __restrict__ ubp) {
    int i = blockIdx.x*256 + threadIdx.x;          // 384*256 total
    int r = i >> 8, c = i & 255;
    gWb[i] = __float2bfloat16(r < 341 ? gW[r*256 + c] : 0.f);
    uWb[i] = __float2bfloat16(r < 341 ? uW[r*256 + c] : 0.f);
    if (i < 384) {
        gbp[i] = i < 341 ? gb[i] : 0.f;
        ubp[i] = i < 341 ? ub[i] : 0.f;
    }
}

__global__ void k_prep_down(const float* __restrict__ dW, bf16* __restrict__ dWb) {
    int i = blockIdx.x*256 + threadIdx.x;          // 256*384 total
    int r = i / 384, c = i % 384;
    dWb[i] = __float2bfloat16(c < 341 ? dW[r*341 + c] : 0.f);
}

// ---------------- LayerNorm 1: f32 -> bf16 ----------------
__global__ __launch_bounds__(256) void k_ln1(const float* __restrict__ x,
        const float* __restrict__ w, const float* __restrict__ b,
        bf16* __restrict__ nx) {
    int wave = threadIdx.x >> 6, lane = threadIdx.x & 63;
    long tok = (long)blockIdx.x * 4 + wave;
    float4 v = ((const float4*)(x + tok*HDIM))[lane];
    float s = v.x + v.y + v.z + v.w;
    float q = v.x*v.x + v.y*v.y + v.z*v.z + v.w*v.w;
    #pragma unroll
    for (int m = 1; m < 64; m <<= 1) { s += __shfl_xor(s, m, 64); q += __shfl_xor(q, m, 64); }
    float mean = s * (1.0f/HDIM);
    float rs = rsqrtf(q*(1.0f/HDIM) - mean*mean + 1e-5f);
    float4 wv = ((const float4*)w)[lane];
    float4 bv = ((const float4*)b)[lane];
    bf16 tmp[4];
    tmp[0] = __float2bfloat16((v.x-mean)*rs*wv.x + bv.x);
    tmp[1] = __float2bfloat16((v.y-mean)*rs*wv.y + bv.y);
    tmp[2] = __float2bfloat16((v.z-mean)*rs*wv.z + bv.z);
    tmp[3] = __float2bfloat16((v.w-mean)*rs*wv.w + bv.w);
    *(ushort4*)(nx + tok*HDIM + lane*4) = *(ushort4*)tmp;
}

// ---------------- LayerNorm 2 + residual: f16 mlp + f32 x -> f32 out ----------------
__global__ __launch_bounds__(256) void k_ln2(const f16* __restrict__ mlp,
        const float* __restrict__ x, const float* __restrict__ w,
        const float* __restrict__ b, float* __restrict__ out) {
    int wave = threadIdx.x >> 6, lane = threadIdx.x & 63;
    long tok = (long)blockIdx.x * 4 + wave;
    const f16* mr = mlp + tok*HDIM + lane*4;
    float4 v; v.x = (float)mr[0]; v.y = (float)mr[1]; v.z = (float)mr[2]; v.w = (float)mr[3];
    float s = v.x + v.y + v.z + v.w;
    float q = v.x*v.x + v.y*v.y + v.z*v.z + v.w*v.w;
    #pragma unroll
    for (int m = 1; m < 64; m <<= 1) { s += __shfl_xor(s, m, 64); q += __shfl_xor(q, m, 64); }
    float mean = s * (1.0f/HDIM);
    float rs = rsqrtf(q*(1.0f/HDIM) - mean*mean + 1e-5f);
    float4 wv = ((const float4*)w)[lane];
    float4 bv = ((const float4*)b)[lane];
    float4 xv = ((const float4*)(x + tok*HDIM))[lane];
    float4 ov;
    ov.x = (v.x-mean)*rs*wv.x + bv.x + xv.x;
    ov.y = (v.y-mean)*rs*wv.y + bv.y + xv.y;
    ov.z = (v.z-mean)*rs*wv.z + bv.z + xv.z;
    ov.w = (v.w-mean)*rs*wv.w + bv.w + xv.w;
    ((float4*)(out + tok*HDIM))[lane] = ov;
}

// ---------------- GEMM: C[M x N] = A[M x K] * B[N x K]^T + bias ----------------
enum { MODE_F16 = 0, MODE_GELU_F16 = 1, MODE_MUL_BF16 = 2 };

template<int MODE>
__global__ __launch_bounds__(256) void k_gemm(
    const bf16* __restrict__ A, const bf16* __restrict__ Bm,
    const float* __restrict__ bias, void* __restrict__ Cv,
    const f16* __restrict__ gatebuf,
    int K, int lda, int ldb, int ldc, int ldg)
{
    // BM=128, BN=64, BK=64; rows stored as 64 bf16 = 128B = 8x16B slots, XOR-swizzled
    __shared__ char Al[128*128];
    __shared__ char Bl[64*128];
    const int tid = threadIdx.x;
    const long bm = (long)blockIdx.x * 128;
    const int bn = blockIdx.y * 64;
    const int wave = tid >> 6, lane = tid & 63;
    const int wm = wave >> 1, wn = wave & 1;        // 2x2 waves, each 64x32
    const int l16 = lane & 15, lq = lane >> 4;
    f32x4 acc[4][2] = {};
    for (int k0 = 0; k0 < K; k0 += 64) {
        #pragma unroll
        for (int p = 0; p < 4; ++p) {               // A: 128 rows x 8 chunks
            int ci = tid + p*256;
            int row = ci >> 3, s = ci & 7;
            uint4 d = *(const uint4*)(A + (bm + row)*lda + k0 + s*8);
            *(uint4*)(Al + row*128 + ((s ^ (row&7))<<4)) = d;
        }
        #pragma unroll
        for (int p = 0; p < 2; ++p) {               // B: 64 rows x 8 chunks
            int ci = tid + p*256;
            int row = ci >> 3, s = ci & 7;
            uint4 d = *(const uint4*)(Bm + (long)(bn + row)*ldb + k0 + s*8);
            *(uint4*)(Bl + row*128 + ((s ^ (row&7))<<4)) = d;
        }
        __syncthreads();
        #pragma unroll
        for (int kc = 0; kc < 2; ++kc) {
            bf16x8 bf[2];
            #pragma unroll
            for (int fn = 0; fn < 2; ++fn) {
                int row = wn*32 + fn*16 + l16;
                int slot = (kc<<2) + lq;
                bf[fn] = *(const bf16x8*)(Bl + row*128 + ((slot ^ (row&7))<<4));
            }
            #pragma unroll
            for (int fm = 0; fm < 4; ++fm) {
                int row = wm*64 + fm*16 + l16;
                int slot = (kc<<2) + lq;
                bf16x8 af = *(const bf16x8*)(Al + row*128 + ((slot ^ (row&7))<<4));
                acc[fm][0] = __builtin_amdgcn_mfma_f32_16x16x32_bf16(af, bf[0], acc[fm][0], 0,0,0);
                acc[fm][1] = __builtin_amdgcn_mfma_f32_16x16x32_bf16(af, bf[1], acc[fm][1], 0,0,0);
            }
        }
        __syncthreads();
    }
    #pragma unroll
    for (int fm = 0; fm < 4; ++fm) {
        #pragma unroll
        for (int fn = 0; fn < 2; ++fn) {
            int n = bn + wn*32 + fn*16 + l16;
            float bv = bias[n];
            #pragma unroll
            for (int r = 0; r < 4; ++r) {
                long m = bm + wm*64 + fm*16 + lq*4 + r;
                float v = acc[fm][fn][r] + bv;
                if constexpr (MODE == MODE_F16) {
                    ((f16*)Cv)[m*ldc + n] = (f16)v;
                } else if constexpr (MODE == MODE_GELU_F16) {
                    ((f16*)Cv)[m*ldc + n] = (f16)gelu_tanh(v);
                } else {
                    float g = (float)gatebuf[m*ldg + n];
                    ((bf16*)Cv)[m*ldc + n] = __float2bfloat16(g * v);
                }
            }
        }
    }
}

// ---------------- sLSTM scan: 64 blocks (1 batch each), 512 threads ----------------
// k-split layout: kg = tid>>7 (4 k-groups of 64 k-values), gb = tid&127.
// Thread computes partial dots for 8 gates g = gb + 128*m over k in [kg*64, kg*64+64).
// R chunks: m=0..5 in VGPRs (48 uint4 = 192 regs), m=6,7 in LDS ([s][tid] layout,
// conflict-free). h broadcast read is only 8 uint4/thread/step (vs 32 in R1/R2).
// Partials reduced via 16KB LDS buffer; epilogue on tid<256 (wave-uniform).
// amdgpu_waves_per_eu(1,2) pins <=2 waves/SIMD -> 256-VGPR budget, no scratch spill.
#define RLDS_BYTES (2*8*8192)                     // 131072: [m'][s][tid] uint4
#define SCAN_SMEM (RLDS_BYTES + 512 + 4*1024*4)   // + h_u + partials = 147968

__global__ __launch_bounds__(512) __attribute__((amdgpu_waves_per_eu(1, 2)))
void k_scan(const f16* __restrict__ xW, const f16* __restrict__ Rf,
            bf16* __restrict__ h_out)
{
    extern __shared__ char sm[];
    char* Rl0     = sm;                              // m=6: addr = s*8192 + tid*16
    char* Rl1     = sm + 65536;                      // m=7
    unsigned* h_u = (unsigned*)(sm + RLDS_BYTES);    // 128 u32 = 256 f16
    float* part   = (float*)(sm + RLDS_BYTES + 512); // [4][1024] f32
    const int tid = threadIdx.x;
    const int b   = blockIdx.x;
    const int kg  = tid >> 7;                        // 0..3
    const int gb  = tid & 127;
    const int j   = tid & 255;

    // ---- one-time: load R chunks (gates g = gb+128m, k-slice [kg*64, kg*64+64)) ----
    uint4 Rq[48];
    #pragma unroll
    for (int m = 0; m < 6; ++m) {
        const uint4* rp = (const uint4*)(Rf + (long)(gb + 128*m)*256 + kg*64);
        #pragma unroll
        for (int s = 0; s < 8; ++s) Rq[m*8 + s] = rp[s];
    }
    {
        const uint4* rp6 = (const uint4*)(Rf + (long)(gb + 128*6)*256 + kg*64);
        const uint4* rp7 = (const uint4*)(Rf + (long)(gb + 128*7)*256 + kg*64);
        #pragma unroll
        for (int s = 0; s < 8; ++s) {
            *(uint4*)(Rl0 + s*8192 + tid*16) = rp6[s];
            *(uint4*)(Rl1 + s*8192 + tid*16) = rp7[s];
        }
    }
    if (tid < 128) h_u[tid] = 0u;

    float cst = 0.f, nst = 0.f, mst = 0.f;
    const f16* xrow = xW + (long)b * TT * G4;
    bf16* hrow = h_out + (long)b * TT * HDIM;
    const uint4* h4 = ((const uint4*)h_u) + (kg << 3);
    __syncthreads();

    for (int t = 0; t < TT; ++t) {
        // xw for this thread's epilogue gates — issued early, consumed ~1300cyc later
        float xz = (float)xrow[j];
        float xi = (float)xrow[j + 256];
        float xf = (float)xrow[j + 512];
        float xo = (float)xrow[j + 768];

        float a[8] = {0.f,0.f,0.f,0.f,0.f,0.f,0.f,0.f};
        #pragma unroll
        for (int s = 0; s < 8; ++s) {
            uint4 hv = h4[s];                        // broadcast (uniform addr/wave)
            #pragma unroll
            for (int m = 0; m < 6; ++m) {
                uint4 rv = Rq[m*8 + s];
                a[m] = dot2f(rv.x, hv.x, a[m]);
                a[m] = dot2f(rv.y, hv.y, a[m]);
                a[m] = dot2f(rv.z, hv.z, a[m]);
                a[m] = dot2f(rv.w, hv.w, a[m]);
            }
            uint4 r6 = *(const uint4*)(Rl0 + s*8192 + tid*16);
            a[6] = dot2f(r6.x, hv.x, a[6]);
            a[6] = dot2f(r6.y, hv.y, a[6]);
            a[6] = dot2f(r6.z, hv.z, a[6]);
            a[6] = dot2f(r6.w, hv.w, a[6]);
            uint4 r7 = *(const uint4*)(Rl1 + s*8192 + tid*16);
            a[7] = dot2f(r7.x, hv.x, a[7]);
            a[7] = dot2f(r7.y, hv.y, a[7]);
            a[7] = dot2f(r7.z, hv.z, a[7]);
            a[7] = dot2f(r7.w, hv.w, a[7]);
        }
        #pragma unroll
        for (int m = 0; m < 8; ++m)
            part[kg*1024 + gb + 128*m] = a[m];       // [kg][g], conflict-free writes
        __syncthreads();

        if (tid < 256) {
            float pz = part[j]     + part[1024 + j]     + part[2048 + j]     + part[3072 + j]     + xz;
            float pi = part[j+256] + part[1024 + j+256] + part[2048 + j+256] + part[3072 + j+256] + xi;
            float pf = part[j+512] + part[1024 + j+512] + part[2048 + j+512] + part[3072 + j+512] + xf;
            float po = part[j+768] + part[1024 + j+768] + part[2048 + j+768] + part[3072 + j+768] + xo;
            float e = __expf(-2.0f * fabsf(pz));
            float z = copysignf((1.0f - e) / (1.0f + e), pz);
            float o = 1.0f / (1.0f + __expf(-po));
            float mn = fmaxf(pf + mst, pi);
            float ig = __expf(pi - mn);
            float fg = __expf(pf + mst - mn);
            cst = fg*cst + ig*z;
            nst = fg*nst + ig;
            mst = mn;
            float h = o * (cst / nst);
            ((f16*)h_u)[tid] = (f16)h;
            hrow[tid] = __float2bfloat16(h);
        }
        __syncthreads();

        xrow += G4;
        hrow += HDIM;
    }
}

// ---------------- launch ----------------
extern "C" void kernel_launch(void* const* d_in, const int* in_sizes, int n_in,
                              void* d_out, int out_size, void* d_ws, size_t ws_size,
                              hipStream_t stream) {
    const float* x     = (const float*)d_in[0];
    const float* ln1w  = (const float*)d_in[1];
    const float* ln1b  = (const float*)d_in[2];
    const float* W     = (const float*)d_in[3];
    const float* R     = (const float*)d_in[4];
    const float* bg    = (const float*)d_in[5];
    const float* upW   = (const float*)d_in[6];
    const float* upb   = (const float*)d_in[7];
    const float* gateW = (const float*)d_in[8];
    const float* gateb = (const float*)d_in[9];
    const float* downW = (const float*)d_in[10];
    const float* downb = (const float*)d_in[11];
    const float* ln2w  = (const float*)d_in[12];
    const float* ln2b  = (const float*)d_in[13];

    char* ws = (char*)d_ws;
    size_t off = 0;
    auto alloc = [&](size_t bytes) { char* p = ws + off; off += (bytes + 255) & ~255ULL; return p; };
    f16*  mlp16   = (f16*)alloc((size_t)NTOK*HDIM*2);     // holds nx first, then mlp (disjoint lifetimes)
    char* regionB = alloc((size_t)NTOK*G4*2);             // xW, then gate_out+prod
    bf16* h       = (bf16*)alloc((size_t)NTOK*HDIM*2);
    bf16* Wb      = (bf16*)alloc(262144*2);
    f16*  Rf      = (f16*)alloc(262144*2);
    bf16* gWb     = (bf16*)alloc((size_t)MPAD*256*2);
    bf16* uWb     = (bf16*)alloc((size_t)MPAD*256*2);
    bf16* dWb     = (bf16*)alloc((size_t)256*MPAD*2);
    float* gbp    = (float*)alloc(MPAD*4);
    float* ubp    = (float*)alloc(MPAD*4);

    bf16* nx       = (bf16*)mlp16;                        // phase 1 use of that region
    f16*  xWb      = (f16*)regionB;                       // 131072 x 1024 f16
    f16*  gate_out = (f16*)regionB;                       // reuse after scan: 131072 x 384 f16
    bf16* prod     = (bf16*)(regionB + (size_t)NTOK*MPAD*2);

    hipFuncSetAttribute(reinterpret_cast<const void*>(&k_scan),
                        hipFuncAttributeMaxDynamicSharedMemorySize, SCAN_SMEM);

    k_prep_wr  <<<1024, 256, 0, stream>>>(W, R, Wb, Rf);
    k_prep_gu  <<<384, 256, 0, stream>>>(gateW, upW, gateb, upb, gWb, uWb, gbp, ubp);
    k_prep_down<<<384, 256, 0, stream>>>(downW, dWb);
    k_ln1      <<<NTOK/4, 256, 0, stream>>>(x, ln1w, ln1b, nx);
    // xW = nx @ W^T + b   (f16 out)
    k_gemm<MODE_F16><<<dim3(1024, 16), 256, 0, stream>>>(nx, Wb, bg, xWb, nullptr, 256, 256, 256, 1024, 0);
    // sequential sLSTM scan
    k_scan     <<<64, 512, SCAN_SMEM, stream>>>(xWb, Rf, h);
    // gate = gelu(h @ gateW^T + gate_b)  (f16)
    k_gemm<MODE_GELU_F16><<<dim3(1024, 6), 256, 0, stream>>>(h, gWb, gbp, gate_out, nullptr, 256, 256, 256, MPAD, 0);
    // prod = gate * (h @ upW^T + up_b)   (bf16, padded cols auto-zero)
    k_gemm<MODE_MUL_BF16><<<dim3(1024, 6), 256, 0, stream>>>(h, uWb, ubp, prod, gate_out, 256, 256, 256, MPAD, MPAD);
    // mlp = prod @ downW^T + down_b      (f16 out, K=384)
    k_gemm<MODE_F16><<<dim3(1024, 4), 256, 0, stream>>>(prod, dWb, downb, mlp16, nullptr, MPAD, MPAD, MPAD, HDIM, 0);
    // out = LN(mlp) + x
    k_ln2      <<<NTOK/4, 256, 0, stream>>>(mlp16, x, ln2w, ln2b, (float*)d_out);
}